// Round 11
// baseline (167.645 us; speedup 1.0000x reference)
//
#include <hip/hip_runtime.h>
#include <math.h>

#define NN 8192
#define DD 512

constexpr float SCALE_C = 0.1f;
constexpr float LN_EPS_C = 1e-6f;
constexpr float NORM_EPS_C = 1e-12f;
constexpr float CBIG = 32768.0f;        // P stored as P*2^15 in fp8
constexpr float INV_CBIG = 1.0f / 32768.0f;

typedef __attribute__((ext_vector_type(8))) short bf16x8;
typedef __attribute__((ext_vector_type(4))) float f32x4;

#define MFMA16(a, b, c) __builtin_amdgcn_mfma_f32_16x16x32_bf16((a), (b), (c), 0, 0, 0)
#define MFMA8(a, b, c)                                                        \
  __builtin_amdgcn_mfma_f32_16x16x32_fp8_fp8((long)(a), (long)(b), (c), 0, 0, 0)

#define GLL16(g, l)                                                        \
  __builtin_amdgcn_global_load_lds(                                        \
      (const __attribute__((address_space(1))) unsigned int*)(g),          \
      (__attribute__((address_space(3))) unsigned int*)(l), 16, 0, 0)

#define WAITV4() asm volatile("s_waitcnt vmcnt(4)" ::: "memory")
#define WAITV0() asm volatile("s_waitcnt vmcnt(0)" ::: "memory")
#define WAITLGKM0() asm volatile("s_waitcnt lgkmcnt(0)" ::: "memory")
#define FENCE() asm volatile("" ::: "memory")
#define BAR() __builtin_amdgcn_s_barrier()

__device__ inline unsigned short f2bf(float f) {
  unsigned int u = __builtin_bit_cast(unsigned int, f);
  unsigned int r = (u + 0x7FFFu + ((u >> 16) & 1u)) >> 16;
  return (unsigned short)r;
}

// f32 -> fp8 e4m3fn, RNE, POSITIVE NORMAL ONLY (valid for E=exp(S) in [0.37,2.72])
__device__ inline unsigned int f2fp8n(float f) {
  unsigned int a = __builtin_bit_cast(unsigned int, f);
  unsigned int r = a + 0x7FFFFu + ((a >> 20) & 1u);
  return (r >> 20) - 960u;
}

// f32 -> fp8 e4m3fn (OCP), RNE, subnormal-aware (for x values in k_prep2)
__device__ inline unsigned int f2fp8(float f) {
  unsigned int u = __builtin_bit_cast(unsigned int, f);
  unsigned int s = (u >> 24) & 0x80u;
  unsigned int a = u & 0x7fffffffu;
  if (a >= 0x3C800000u) {  // >= 2^-6: normal
    unsigned int r = a + 0x7FFFFu + ((a >> 20) & 1u);
    return s | ((r >> 20) - 960u);
  }
  float af = __builtin_bit_cast(float, a);
  return s | (unsigned int)(int)rintf(af * 512.0f);  // subnormal: m * 2^-9
}

// fp8 e4m3 (positive, normal) -> f32
__device__ inline float fp82f(unsigned int b) {
  return __builtin_bit_cast(float, (b + 960u) << 20);
}

// ---------------- K0 (fused): xnb = bf16(x/||x||) AND xT8[d][j] = fp8(x[j][d]).
// 512 blocks x 256 threads, 16 rows per block. x read ONCE (was twice).
__global__ __launch_bounds__(256) void k_prep2(const float* __restrict__ x,
                                               unsigned short* __restrict__ xnb,
                                               unsigned char* __restrict__ xT8) {
  __shared__ unsigned int T8w[16][130];  // 16 rows x 512 fp8 bytes (word-packed, +2 pad)
  const int j0 = blockIdx.x * 16;
  const int t = threadIdx.x;
  const int tr = t >> 4, tc = t & 15;   // 16 threads per row
  const int row = j0 + tr;
  const float* xr = x + (size_t)row * DD;
  float4 v[8];
  float ss = 0.f;
#pragma unroll
  for (int k = 0; k < 8; ++k) {
    v[k] = *(const float4*)(xr + tc * 4 + k * 64);
    ss += v[k].x * v[k].x + v[k].y * v[k].y + v[k].z * v[k].z + v[k].w * v[k].w;
  }
#pragma unroll
  for (int off = 1; off < 16; off <<= 1) ss += __shfl_xor(ss, off);
  const float rn = 1.0f / fmaxf(sqrtf(ss), NORM_EPS_C);
#pragma unroll
  for (int k = 0; k < 8; ++k) {
    ushort4 o;
    o.x = f2bf(v[k].x * rn);
    o.y = f2bf(v[k].y * rn);
    o.z = f2bf(v[k].z * rn);
    o.w = f2bf(v[k].w * rn);
    *(ushort4*)(xnb + (size_t)row * DD + tc * 4 + k * 64) = o;
    T8w[tr][tc + k * 16] = f2fp8(v[k].x) | (f2fp8(v[k].y) << 8) |
                           (f2fp8(v[k].z) << 16) | (f2fp8(v[k].w) << 24);
  }
  __syncthreads();
  // transpose out: each thread handles 2 d-values, gathers 16 bytes (column d)
#pragma unroll
  for (int q = 0; q < 2; ++q) {
    const int d = t + q * 256;
    const unsigned char* col = (const unsigned char*)&T8w[0][0] + d;  // stride 520
    unsigned int wds[4];
#pragma unroll
    for (int p = 0; p < 4; ++p)
      wds[p] = (unsigned int)col[(p * 4 + 0) * 520] |
               ((unsigned int)col[(p * 4 + 1) * 520] << 8) |
               ((unsigned int)col[(p * 4 + 2) * 520] << 16) |
               ((unsigned int)col[(p * 4 + 3) * 520] << 24);
    *(uint4*)&xT8[(size_t)d * NN + j0] = make_uint4(wds[0], wds[1], wds[2], wds[3]);
  }
}

// ---------------- K1: symmetric S-GEMM -> tiled fp8 E + l partials ------------
// NEW (round 11): 256x256 tile, BK=64, 8 waves (2Mx4N), 512 threads,
// SINGLE-BARRIER / FULL-TILE-LEAD schedule: at the top of tile kt, ONE
// vmcnt(0) (drains tile kt's 8 loads, issued a full tile earlier) + ONE
// barrier; then ALL 4 half-tiles of kt+1 are staged into the other buffer
// (freed by this same barrier). One tile's MFMA (~640-900 cy/SIMD) exceeds
// L2/L3 latency, so prefetch hides intra-block — no cross-block overlap
// needed (fixes r4/r6's short lead without r1/r9's occupancy trap).
// Fragment mapping / swizzle / reductions reused from r6 (correctness-proven);
// epilogue in r7 convention (transposed tile -> lower slot, word-granular).
// Diag blocks' (1,0) sub-tile lands in an upper slot later overwritten by
// k_scale2's mirror (harmless, r6-proven). 128 KB LDS, 1 block/CU.
__global__ __launch_bounds__(512, 2) void k_rowsumE(const unsigned short* __restrict__ xnb,
                                                    float* __restrict__ lpart,
                                                    unsigned char* __restrict__ E8) {
  __shared__ __align__(16) unsigned char POOL[131072];
  // GEMM: buf b at b*65536 (A [256 rows][128B] at +0, B at +32768)
  // Epilogue overlay: Et2[256][264] at +0 (67584B), redrow at +69632 (4KB),
  //                   redcol at +73728 (2KB)

  int b = blockIdx.x, BI = 0;
  while (b >= 32 - BI) { b -= 32 - BI; ++BI; }
  const int BJ = BI + b;
  const int i0 = BI * 256, j0 = BJ * 256;
  const int diag = (BI == BJ);

  const int t = threadIdx.x;
  const int w = t >> 6, l = t & 63;
  const int lr = l & 15, lg = l >> 4;
  const int wr = w >> 2, wc = w & 3;  // 2M x 4N wave grid

  // Stage one half-tile (128 rows x 64 K = 16 KB) of global rows Rglob.. into
  // LDS at LbOff. Linear LDS dest (wave-uniform base + lane*16); the chunk
  // swizzle (c ^= row&7) is applied to the GLOBAL source address (rule 21).
#define ST_HALF(Rglob, LbOff, ktv)                                             \
  do {                                                                         \
    _Pragma("unroll") for (int q_ = 0; q_ < 2; ++q_) {                         \
      const int f_ = q_ * 512 + t;                                             \
      const int row_ = f_ >> 3, c_ = f_ & 7;                                   \
      GLL16((const unsigned char*)xnb + (size_t)((Rglob) + row_) * 1024 +      \
                (ktv) * 128 + ((c_ ^ (row_ & 7)) << 4),                        \
            POOL + (LbOff) + q_ * 8192 + w * 1024);                            \
    }                                                                          \
  } while (0)

  // prologue: stage K-tile 0 (4 half-tiles = 8 loads/thread) into buf0
  ST_HALF(i0, 0, 0);
  ST_HALF(i0 + 128, 16384, 0);
  ST_HALF(j0, 32768, 0);
  ST_HALF(j0 + 128, 49152, 0);

  f32x4 acc[8][4] = {};

  for (int kt = 0; kt < 8; ++kt) {
    const int buf = kt & 1;
    const unsigned char* Ab = POOL + buf * 65536;
    const unsigned char* Bb = Ab + 32768;
    // ONE wait + ONE barrier per tile. Nothing else is outstanding, so
    // vmcnt(0) exactly means "tile kt fully landed" (issued one tile ago).
    WAITV0();
    BAR(); FENCE();
    if (kt + 1 < 8) {  // stage ALL of tile kt+1 into the buffer freed above
      const int nb = (buf ^ 1) * 65536;
      ST_HALF(i0, nb + 0, kt + 1);
      ST_HALF(i0 + 128, nb + 16384, kt + 1);
      ST_HALF(j0, nb + 32768, kt + 1);
      ST_HALF(j0 + 128, nb + 49152, kt + 1);
    }
    bf16x8 bv[4][2];
#pragma unroll
    for (int fn = 0; fn < 4; ++fn) {
      const int row = wc * 64 + fn * 16 + lr;
#pragma unroll
      for (int kk = 0; kk < 2; ++kk)
        bv[fn][kk] = *(const bf16x8*)(Bb + row * 128 +
                                      (((kk * 4 + lg) ^ (row & 7)) << 4));
    }
#pragma unroll
    for (int p = 0; p < 4; ++p) {
      bf16x8 af[2][2];
#pragma unroll
      for (int fq = 0; fq < 2; ++fq) {
        const int row = wr * 128 + (2 * p + fq) * 16 + lr;
#pragma unroll
        for (int kk = 0; kk < 2; ++kk)
          af[fq][kk] = *(const bf16x8*)(Ab + row * 128 +
                                        (((kk * 4 + lg) ^ (row & 7)) << 4));
      }
      __builtin_amdgcn_s_setprio(1);
#pragma unroll
      for (int kk = 0; kk < 2; ++kk)
#pragma unroll
        for (int fq = 0; fq < 2; ++fq)
#pragma unroll
          for (int fn = 0; fn < 4; ++fn)
            acc[2 * p + fq][fn] =
                MFMA16(af[fq][kk], bv[fn][kk], acc[2 * p + fq][fn]);
      __builtin_amdgcn_s_setprio(0);
    }
  }
  BAR(); FENCE();  // all waves done reading POOL before epilogue overlay

  // ---- epilogue: streaming exp -> sums + packed fp8 ----
  unsigned int ebw[8][4];
  float rsum[8][4] = {};
  float csum[4] = {};
#pragma unroll
  for (int fm = 0; fm < 8; ++fm)
#pragma unroll
    for (int fn = 0; fn < 4; ++fn) {
      unsigned int pw = 0;
#pragma unroll
      for (int rr = 0; rr < 4; ++rr) {
        float e = __expf(acc[fm][fn][rr]);
        rsum[fm][rr] += e;
        csum[fn] += e;
        pw |= f2fp8n(e) << (8 * rr);
      }
      ebw[fm][fn] = pw;
    }

  float* redrow = (float*)(POOL + 69632);  // [2(wr)][4(wc)][128] row-sums
  float* redcol = (float*)(POOL + 73728);  // [2(wr)][256] col-sums
#pragma unroll
  for (int fm = 0; fm < 8; ++fm)
#pragma unroll
    for (int rr = 0; rr < 4; ++rr) {
      float s = rsum[fm][rr];
#pragma unroll
      for (int off = 1; off < 16; off <<= 1) s += __shfl_xor(s, off);
      if (lr == 0) redrow[(wr * 4 + wc) * 128 + fm * 16 + lg * 4 + rr] = s;
    }
  if (!diag) {
#pragma unroll
    for (int fn = 0; fn < 4; ++fn) {
      float cs = csum[fn];
      cs += __shfl_xor(cs, 16);
      cs += __shfl_xor(cs, 32);
      if (lg == 0) redcol[wr * 256 + wc * 64 + fn * 16 + lr] = cs;
    }
  }

  // transposed bounce: Et2[col][row] (word writes: rr bytes contiguous)
  unsigned char(*Et2)[264] = (unsigned char(*)[264])POOL;  // 67584 B
#pragma unroll
  for (int fm = 0; fm < 8; ++fm)
#pragma unroll
    for (int fn = 0; fn < 4; ++fn)
      *(unsigned int*)&Et2[wc * 64 + fn * 16 + lr][wr * 128 + fm * 16 + lg * 4] =
          ebw[fm][fn];
  __syncthreads();

  // write 4 transposed 128x128 tiles: slot ((2BJ+bq)*64 + (2BI+a)) holds
  // T[jj][ii] = E[a*128+ii][bq*128+jj] = Et2[bq*128+jj][a*128+ii]
#pragma unroll
  for (int a = 0; a < 2; ++a)
#pragma unroll
    for (int bq = 0; bq < 2; ++bq) {
      unsigned char* dst =
          E8 + ((size_t)((2 * BJ + bq) * 64 + (2 * BI + a)) << 14);
#pragma unroll
      for (int q = 0; q < 2; ++q) {
        const int f = q * 512 + t;
        const int rr_ = f >> 3, cc_ = (f & 7) * 16;
        *(uint4*)(dst + f * 16) =
            *(const uint4*)&Et2[bq * 128 + rr_][a * 128 + cc_];
      }
    }
  // lpart: rows (always, 2 col-block slots), cols (off-diag only)
  if (t < 256) {
    const int row = t & 127, wrx = t >> 7;
    const float h0 = redrow[(wrx * 4 + 0) * 128 + row] +
                     redrow[(wrx * 4 + 1) * 128 + row];
    const float h1 = redrow[(wrx * 4 + 2) * 128 + row] +
                     redrow[(wrx * 4 + 3) * 128 + row];
    lpart[(size_t)(2 * BJ) * NN + i0 + wrx * 128 + row] = h0;
    lpart[(size_t)(2 * BJ + 1) * NN + i0 + wrx * 128 + row] = h1;
  } else if (!diag) {
    const int col = t - 256;
    const float tot = redcol[col] + redcol[256 + col];
    lpart[(size_t)(2 * BI + (col >> 7)) * NN + j0 + col] = tot;
  }
}

// ---------------- K1b: rl = 2^15 / sum(lpart over 64 slots) ----------------
__global__ __launch_bounds__(256) void k_recip(const float* __restrict__ lpart,
                                               float* __restrict__ rl) {
  const int i = blockIdx.x * 256 + threadIdx.x;
  float s = 0.f;
  for (int c = 0; c < 64; ++c) s += lpart[(size_t)c * NN + i];
  rl[i] = CBIG / s;
}

// ---------------- K2: rowsumE wrote the LOWER slot (tj,ti); scale it in place
// (rows are j-range, cols i-range: factor rl[j0+r]+rl[i0+c]) and mirror the
// scaled tile into the UPPER slot (ti,tj) via LDS word-level 4x4 transpose. ----
__global__ __launch_bounds__(256) void k_scale2(unsigned char* __restrict__ P,
                                                const float* __restrict__ rl) {
  __shared__ unsigned int T32[128][35];  // scaled tile, word-granular, padded
  int b = blockIdx.x, ti = 0;
  while (b >= 64 - ti) { b -= 64 - ti; ++ti; }
  const int tj = ti + b;
  const int i0 = ti * 128, j0 = tj * 128;
  const int t = threadIdx.x;
  unsigned char* tileC = P + ((size_t)(tj * 64 + ti) << 14);  // lower slot

  // pass 1: read + scale + write canonical (in place) + stage words into LDS
#pragma unroll
  for (int q = 0; q < 4; ++q) {
    const int f = t + q * 256;      // 1024 chunks of 16B
    const int r = f >> 3;           // row within tile = global row j0+r
    const int c0 = (f & 7) * 16;    // col within tile = global col i0+c
    uint4 v = *(const uint4*)(tileC + f * 16);
    const float rlr = rl[j0 + r];
    float rlc[16];
#pragma unroll
    for (int p = 0; p < 4; ++p) {
      float4 r4 = *(const float4*)(rl + i0 + c0 + p * 4);
      rlc[p * 4 + 0] = r4.x; rlc[p * 4 + 1] = r4.y;
      rlc[p * 4 + 2] = r4.z; rlc[p * 4 + 3] = r4.w;
    }
    unsigned int wsrc[4] = {v.x, v.y, v.z, v.w};
    unsigned int wdst[4];
#pragma unroll
    for (int p = 0; p < 4; ++p) {
      unsigned int in = wsrc[p], out = 0;
#pragma unroll
      for (int k = 0; k < 4; ++k) {
        float e = fp82f((in >> (8 * k)) & 0xffu);
        out |= f2fp8n(e * (rlr + rlc[p * 4 + k])) << (8 * k);
      }
      wdst[p] = out;
      T32[r][(c0 >> 2) + p] = out;
    }
    *(uint4*)(tileC + f * 16) = make_uint4(wdst[0], wdst[1], wdst[2], wdst[3]);
  }
  if (ti == tj) return;  // diagonal: no mirror needed
  __syncthreads();

  // pass 2: upper slot (ti,tj): out[r2][c] = scaled[c][r2]
  unsigned char* tileT = P + ((size_t)(ti * 64 + tj) << 14);
  {
    const int rg = t >> 3;        // out row group (4 rows): r2 = rg*4
    const int cc = t & 7;         // out col chunk: c2 = cc*16
    const int c2 = cc * 16;
    unsigned int o[4][4];  // o[i][k4]: out row rg*4+i, word k4
#pragma unroll
    for (int k4 = 0; k4 < 4; ++k4) {
      unsigned int a0 = T32[c2 + k4 * 4 + 0][rg];
      unsigned int a1 = T32[c2 + k4 * 4 + 1][rg];
      unsigned int a2 = T32[c2 + k4 * 4 + 2][rg];
      unsigned int a3 = T32[c2 + k4 * 4 + 3][rg];
      unsigned int b0 = (a0 & 0x00FF00FFu) | ((a1 << 8) & 0xFF00FF00u);
      unsigned int b1 = ((a0 >> 8) & 0x00FF00FFu) | (a1 & 0xFF00FF00u);
      unsigned int b2 = (a2 & 0x00FF00FFu) | ((a3 << 8) & 0xFF00FF00u);
      unsigned int b3 = ((a2 >> 8) & 0x00FF00FFu) | (a3 & 0xFF00FF00u);
      o[0][k4] = (b0 & 0x0000FFFFu) | (b2 << 16);
      o[1][k4] = (b1 & 0x0000FFFFu) | (b3 << 16);
      o[2][k4] = (b0 >> 16) | (b2 & 0xFFFF0000u);
      o[3][k4] = (b1 >> 16) | (b3 & 0xFFFF0000u);
    }
#pragma unroll
    for (int i = 0; i < 4; ++i)
      *(uint4*)(tileT + (size_t)(rg * 4 + i) * 128 + c2) =
          make_uint4(o[i][0], o[i][1], o[i][2], o[i][3]);
  }
}

// ---------------- K3: parts[z] = bf16((P8t @ x8) * 2^-15), K-split 4 ----------
// Round-2 proven pipeline + round-8 coalesced C-write via LDS bounce.
__global__ __launch_bounds__(256, 4) void k_pv3(const unsigned char* __restrict__ P8,
                                                const unsigned char* __restrict__ xT8,
                                                unsigned short* __restrict__ parts) {
  __shared__ __align__(16) unsigned char POOL[34816];
  const int i0 = blockIdx.x * 128;
  const int n0 = blockIdx.y * 128;
  const int z = blockIdx.z;
  const int t = threadIdx.x;
  const int w = t >> 6, l = t & 63;
  const int lr = l & 15, lg = l >> 4;
  const int wr = w >> 1, wc = w & 1;
  const int r0 = w * 16 + (l >> 2);
  const int clog = (l & 3) ^ ((r0 >> 1) & 3);
  const unsigned char* Abase = P8 + ((size_t)((i0 >> 7) * 64 + z * 16) << 14) +
                               r0 * 128 + clog * 16;
  const unsigned char* gB = xT8 + (size_t)(n0 + r0) * NN + z * 2048 + clog * 16;

#define PV_STAGE(s, koff)                                                      \
  do {                                                                         \
    const unsigned char* a_ = Abase + (((koff) >> 7) << 14) + ((koff) & 127);  \
    GLL16(a_, POOL + (s) * 8192 + w * 1024);                                   \
    GLL16(a_ + 8192, POOL + (s) * 8192 + 4096 + w * 1024);                     \
    GLL16(gB + (koff), POOL + 16384 + (s) * 8192 + w * 1024);                  \
    GLL16(gB + (size_t)64 * NN + (koff),                                       \
          POOL + 16384 + (s) * 8192 + 4096 + w * 1024);                        \
  } while (0)

  PV_STAGE(0, 0);
  PV_STAGE(1, 64);

  f32x4 acc[4][4] = {};
  for (int ks = 0; ks < 32; ++ks) {
    if (ks + 1 < 32) { WAITV4(); } else { WAITV0(); }
    BAR(); FENCE();
    const char* AS = (const char*)(POOL + (ks & 1) * 8192);
    const char* BS = (const char*)(POOL + 16384 + (ks & 1) * 8192);
    unsigned long long af[4][2], bv[4][2];
#pragma unroll
    for (int fm = 0; fm < 4; ++fm) {
      const int row = wr * 64 + fm * 16 + lr;
      const int swz = (row >> 1) & 3;
#pragma unroll
      for (int kk = 0; kk < 2; ++kk) {
        int off = row * 64 + (((kk * 2 + (lg >> 1)) ^ swz) << 4) + ((lg & 1) << 3);
        af[fm][kk] = *(const unsigned long long*)(AS + off);
      }
    }
#pragma unroll
    for (int fn = 0; fn < 4; ++fn) {
      const int row = wc * 64 + fn * 16 + lr;
      const int swz = (row >> 1) & 3;
#pragma unroll
      for (int kk = 0; kk < 2; ++kk) {
        int off = row * 64 + (((kk * 2 + (lg >> 1)) ^ swz) << 4) + ((lg & 1) << 3);
        bv[fn][kk] = *(const unsigned long long*)(BS + off);
      }
    }
    WAITLGKM0();
    BAR(); FENCE();
    if (ks + 2 < 32) PV_STAGE(ks & 1, (ks + 2) * 64);
#pragma unroll
    for (int kk = 0; kk < 2; ++kk)
#pragma unroll
      for (int fm = 0; fm < 4; ++fm)
#pragma unroll
        for (int fn = 0; fn < 4; ++fn)
          acc[fm][fn] = MFMA8(af[fm][kk], bv[fn][kk], acc[fm][fn]);
  }

  // ---- epilogue: LDS bounce -> coalesced uint4 stores ----
  BAR(); FENCE();  // all waves done reading pipeline LDS
  unsigned short* Pt = (unsigned short*)POOL;  // [128 rows][136 shorts] (272B)
#pragma unroll
  for (int fm = 0; fm < 4; ++fm)
#pragma unroll
    for (int fn = 0; fn < 4; ++fn) {
      const int col = wc * 64 + fn * 16 + lr;
#pragma unroll
      for (int rr = 0; rr < 4; ++rr) {
        const int row = wr * 64 + fm * 16 + lg * 4 + rr;
        Pt[row * 136 + col] = f2bf(acc[fm][fn][rr] * INV_CBIG);
      }
    }
  __syncthreads();
  {
    unsigned short* dst = parts + (size_t)z * NN * DD + (size_t)i0 * DD + n0;
#pragma unroll
    for (int q = 0; q < 8; ++q) {
      const int f = t + q * 256;        // 2048 chunks of 16B
      const int row = f >> 4, ch = f & 15;
      *(uint4*)(dst + (size_t)row * DD + ch * 8) =
          *(const uint4*)&Pt[row * 136 + ch * 8];
    }
  }
}

// ---------------- K4: y = x - SCALE*sum(parts), LayerNorm ----------------
// Round-10 wave-per-row: 2048 blocks x 256 threads, shfl-only reductions.
__global__ __launch_bounds__(256) void k_ln(const float* __restrict__ x,
                                            float* __restrict__ out,
                                            const unsigned short* __restrict__ parts,
                                            const float* __restrict__ gamma,
                                            const float* __restrict__ beta) {
  const int row = blockIdx.x * 4 + (threadIdx.x >> 6);
  const int l = threadIdx.x & 63;
  const int c0 = l * 8;

  float p[8] = {};
#pragma unroll
  for (int s = 0; s < 4; ++s) {
    uint4 q = *(const uint4*)(parts + (size_t)s * NN * DD + (size_t)row * DD + c0);
    unsigned int wq[4] = {q.x, q.y, q.z, q.w};
#pragma unroll
    for (int j = 0; j < 4; ++j) {
      p[2 * j + 0] += __builtin_bit_cast(float, wq[j] << 16);
      p[2 * j + 1] += __builtin_bit_cast(float, wq[j] & 0xFFFF0000u);
    }
  }
  float4 xv0 = *(const float4*)(x + (size_t)row * DD + c0);
  float4 xv1 = *(const float4*)(x + (size_t)row * DD + c0 + 4);
  float y[8];
  y[0] = xv0.x - SCALE_C * p[0];
  y[1] = xv0.y - SCALE_C * p[1];
  y[2] = xv0.z - SCALE_C * p[2];
  y[3] = xv0.w - SCALE_C * p[3];
  y[4] = xv1.x - SCALE_C * p[4];
  y[5] = xv1.y - SCALE_C * p[5];
  y[6] = xv1.z - SCALE_C * p[6];
  y[7] = xv1.w - SCALE_C * p[7];

  float sum = 0.f;
#pragma unroll
  for (int j = 0; j < 8; ++j) sum += y[j];
#pragma unroll
  for (int off = 1; off < 64; off <<= 1) sum += __shfl_xor(sum, off);
  const float mean = sum * (1.0f / DD);

  float d[8], vs = 0.f;
#pragma unroll
  for (int j = 0; j < 8; ++j) {
    d[j] = y[j] - mean;
    vs += d[j] * d[j];
  }
#pragma unroll
  for (int off = 1; off < 64; off <<= 1) vs += __shfl_xor(vs, off);
  const float rstd = rsqrtf(vs * (1.0f / DD) + LN_EPS_C);

  float4 g0 = *(const float4*)(gamma + c0);
  float4 g1 = *(const float4*)(gamma + c0 + 4);
  float4 b0 = *(const float4*)(beta + c0);
  float4 b1 = *(const float4*)(beta + c0 + 4);
  float4 o0, o1;
  o0.x = d[0] * rstd * g0.x + b0.x;
  o0.y = d[1] * rstd * g0.y + b0.y;
  o0.z = d[2] * rstd * g0.z + b0.z;
  o0.w = d[3] * rstd * g0.w + b0.w;
  o1.x = d[4] * rstd * g1.x + b1.x;
  o1.y = d[5] * rstd * g1.y + b1.y;
  o1.z = d[6] * rstd * g1.z + b1.z;
  o1.w = d[7] * rstd * g1.w + b1.w;
  *(float4*)(out + (size_t)row * DD + c0) = o0;
  *(float4*)(out + (size_t)row * DD + c0 + 4) = o1;
}

extern "C" void kernel_launch(void* const* d_in, const int* in_sizes, int n_in,
                              void* d_out, int out_size, void* d_ws, size_t ws_size,
                              hipStream_t stream) {
  const float* x = (const float*)d_in[0];
  const float* gamma = (const float*)d_in[1];
  const float* beta = (const float*)d_in[2];
  float* out = (float*)d_out;

  unsigned short* xnb = (unsigned short*)d_ws;               // 8 MB (bf16 xn)
  unsigned char* xT8 = (unsigned char*)(xnb + (size_t)NN * DD);  // 4 MB (fp8 xT)
  float* lpart = (float*)(xT8 + (size_t)NN * DD);            // 2 MB
  float* rl = lpart + (size_t)64 * NN;                       // 32 KB
  unsigned short* parts = (unsigned short*)(rl + NN);        // 32 MB (4 bf16 slices)
  unsigned char* E8 = (unsigned char*)(parts + (size_t)4 * NN * DD);  // 64 MB tiled
  // total ~110 MB; 162 MB proven available in rounds 4-16

  k_prep2<<<NN / 16, 256, 0, stream>>>(x, xnb, xT8);
  k_rowsumE<<<528, 512, 0, stream>>>(xnb, lpart, E8);
  k_recip<<<NN / 256, 256, 0, stream>>>(lpart, rl);
  k_scale2<<<2080, 256, 0, stream>>>(E8, rl);
  k_pv3<<<dim3(64, 4, 4), 256, 0, stream>>>(E8, xT8, parts);
  k_ln<<<NN / 4, 256, 0, stream>>>(x, out, parts, gamma, beta);
}

// Round 12
// 147.640 us; speedup vs baseline: 1.1355x; 1.1355x over previous
//
#include <hip/hip_runtime.h>
#include <math.h>

#define NN 8192
#define DD 512

constexpr float SCALE_C = 0.1f;
constexpr float LN_EPS_C = 1e-6f;
constexpr float NORM_EPS_C = 1e-12f;
constexpr float CBIG = 32768.0f;        // P stored as P*2^15 in fp8
constexpr float INV_CBIG = 1.0f / 32768.0f;

typedef __attribute__((ext_vector_type(8))) short bf16x8;
typedef __attribute__((ext_vector_type(4))) float f32x4;

#define MFMA16(a, b, c) __builtin_amdgcn_mfma_f32_16x16x32_bf16((a), (b), (c), 0, 0, 0)
#define MFMA8(a, b, c)                                                        \
  __builtin_amdgcn_mfma_f32_16x16x32_fp8_fp8((long)(a), (long)(b), (c), 0, 0, 0)

#define GLL16(g, l)                                                        \
  __builtin_amdgcn_global_load_lds(                                        \
      (const __attribute__((address_space(1))) unsigned int*)(g),          \
      (__attribute__((address_space(3))) unsigned int*)(l), 16, 0, 0)

#define WAITV4() asm volatile("s_waitcnt vmcnt(4)" ::: "memory")
#define WAITV0() asm volatile("s_waitcnt vmcnt(0)" ::: "memory")
#define WAITLGKM0() asm volatile("s_waitcnt lgkmcnt(0)" ::: "memory")
#define FENCE() asm volatile("" ::: "memory")
#define BAR() __builtin_amdgcn_s_barrier()

__device__ inline unsigned short f2bf(float f) {
  unsigned int u = __builtin_bit_cast(unsigned int, f);
  unsigned int r = (u + 0x7FFFu + ((u >> 16) & 1u)) >> 16;
  return (unsigned short)r;
}

// f32 -> fp8 e4m3fn, RNE, POSITIVE NORMAL ONLY (valid for E=exp(S) in [0.37,2.72])
__device__ inline unsigned int f2fp8n(float f) {
  unsigned int a = __builtin_bit_cast(unsigned int, f);
  unsigned int r = a + 0x7FFFFu + ((a >> 20) & 1u);
  return (r >> 20) - 960u;
}

// f32 -> fp8 e4m3fn (OCP), RNE, subnormal-aware (for x values in k_prep2)
__device__ inline unsigned int f2fp8(float f) {
  unsigned int u = __builtin_bit_cast(unsigned int, f);
  unsigned int s = (u >> 24) & 0x80u;
  unsigned int a = u & 0x7fffffffu;
  if (a >= 0x3C800000u) {  // >= 2^-6: normal
    unsigned int r = a + 0x7FFFFu + ((a >> 20) & 1u);
    return s | ((r >> 20) - 960u);
  }
  float af = __builtin_bit_cast(float, a);
  return s | (unsigned int)(int)rintf(af * 512.0f);  // subnormal: m * 2^-9
}

// fp8 e4m3 (positive, normal) -> f32
__device__ inline float fp82f(unsigned int b) {
  return __builtin_bit_cast(float, (b + 960u) << 20);
}

// ---------------- K0 (fused): xnb = bf16(x/||x||) AND xT8[d][j] = fp8(x[j][d]).
// 512 blocks x 256 threads, 16 rows per block. x read ONCE (was twice).
__global__ __launch_bounds__(256) void k_prep2(const float* __restrict__ x,
                                               unsigned short* __restrict__ xnb,
                                               unsigned char* __restrict__ xT8) {
  __shared__ unsigned int T8w[16][130];  // 16 rows x 512 fp8 bytes (word-packed, +2 pad)
  const int j0 = blockIdx.x * 16;
  const int t = threadIdx.x;
  const int tr = t >> 4, tc = t & 15;   // 16 threads per row
  const int row = j0 + tr;
  const float* xr = x + (size_t)row * DD;
  float4 v[8];
  float ss = 0.f;
#pragma unroll
  for (int k = 0; k < 8; ++k) {
    v[k] = *(const float4*)(xr + tc * 4 + k * 64);
    ss += v[k].x * v[k].x + v[k].y * v[k].y + v[k].z * v[k].z + v[k].w * v[k].w;
  }
#pragma unroll
  for (int off = 1; off < 16; off <<= 1) ss += __shfl_xor(ss, off);
  const float rn = 1.0f / fmaxf(sqrtf(ss), NORM_EPS_C);
#pragma unroll
  for (int k = 0; k < 8; ++k) {
    ushort4 o;
    o.x = f2bf(v[k].x * rn);
    o.y = f2bf(v[k].y * rn);
    o.z = f2bf(v[k].z * rn);
    o.w = f2bf(v[k].w * rn);
    *(ushort4*)(xnb + (size_t)row * DD + tc * 4 + k * 64) = o;
    T8w[tr][tc + k * 16] = f2fp8(v[k].x) | (f2fp8(v[k].y) << 8) |
                           (f2fp8(v[k].z) << 16) | (f2fp8(v[k].w) << 24);
  }
  __syncthreads();
  // transpose out: each thread handles 2 d-values, gathers 16 bytes (column d)
#pragma unroll
  for (int q = 0; q < 2; ++q) {
    const int d = t + q * 256;
    const unsigned char* col = (const unsigned char*)&T8w[0][0] + d;  // stride 520
    unsigned int wds[4];
#pragma unroll
    for (int p = 0; p < 4; ++p)
      wds[p] = (unsigned int)col[(p * 4 + 0) * 520] |
               ((unsigned int)col[(p * 4 + 1) * 520] << 8) |
               ((unsigned int)col[(p * 4 + 2) * 520] << 16) |
               ((unsigned int)col[(p * 4 + 3) * 520] << 24);
    *(uint4*)&xT8[(size_t)d * NN + j0] = make_uint4(wds[0], wds[1], wds[2], wds[3]);
  }
}

// ---------------- K1: symmetric S-GEMM (bf16) -> tiled fp8 E + l partials ------
// E8 layout: tile (a,b) contiguous 16 KB at (a*64+b)*16384, row-major inside.
// Round-2 proven 2-slot / 2-barrier / vmcnt(4) pipeline. Round-7: transposed-
// slot-only word-granular bounce. NEW (round 12): LDS squeezed to EXACTLY
// 32768 B (red/red2 overlaid into POOL after the K-loop; explicit sync added)
// -> 5 blocks/CU (was 4). Pure residency change; arithmetic identical.
__global__ __launch_bounds__(256, 4) void k_rowsumE(const unsigned short* __restrict__ xnb,
                                                    float* __restrict__ lpart,
                                                    unsigned char* __restrict__ E8) {
  __shared__ __align__(16) unsigned char POOL[32768];
  // K-loop: 2 x 16 KB stage slots. Epilogue overlay: Et2[128][144] at +0
  // (18432 B), red[4][64] f32 at +18432, red2[4][64] f32 at +19456.

  int b = blockIdx.x, bi = 0;
  while (b >= 64 - bi) { b -= 64 - bi; ++bi; }
  const int bj = bi + b;
  const int i0 = bi * 128, j0 = bj * 128;
  const int diag = (bi == bj);

  const int t = threadIdx.x;
  const int w = t >> 6, l = t & 63;
  const int lr = l & 15, lg = l >> 4;
  const int wr = w >> 1, wc = w & 1;
  const int r0 = w * 16 + (l >> 2);
  const int clog = (l & 3) ^ ((r0 >> 1) & 3);
  const unsigned short* gA = xnb + (size_t)(i0 + r0) * DD + clog * 8;
  const unsigned short* gB = xnb + (size_t)(j0 + r0) * DD + clog * 8;

#define RS_STAGE(s, koff)                                                        \
  do {                                                                           \
    GLL16(gA + (koff), (unsigned short*)(POOL + (s) * 16384) + w * 512);         \
    GLL16(gA + (size_t)64 * DD + (koff),                                         \
          (unsigned short*)(POOL + (s) * 16384 + 4096) + w * 512);               \
    GLL16(gB + (koff), (unsigned short*)(POOL + (s) * 16384 + 8192) + w * 512);  \
    GLL16(gB + (size_t)64 * DD + (koff),                                         \
          (unsigned short*)(POOL + (s) * 16384 + 12288) + w * 512);              \
  } while (0)

  RS_STAGE(0, 0);
  RS_STAGE(1, 32);

  f32x4 acc[4][4] = {};
  for (int ks = 0; ks < 16; ++ks) {
    if (ks + 1 < 16) { WAITV4(); } else { WAITV0(); }
    BAR(); FENCE();
    const char* AS = (const char*)(POOL + (ks & 1) * 16384);
    const char* BS = AS + 8192;
    bf16x8 af[4], bv[4];
#pragma unroll
    for (int fm = 0; fm < 4; ++fm) {
      const int row = wr * 64 + fm * 16 + lr;
      af[fm] = *(const bf16x8*)(AS + row * 64 + ((lg ^ ((row >> 1) & 3)) << 4));
    }
#pragma unroll
    for (int fn = 0; fn < 4; ++fn) {
      const int row = wc * 64 + fn * 16 + lr;
      bv[fn] = *(const bf16x8*)(BS + row * 64 + ((lg ^ ((row >> 1) & 3)) << 4));
    }
    WAITLGKM0();
    BAR(); FENCE();
    if (ks + 2 < 16) RS_STAGE(ks & 1, (size_t)(ks + 2) * 32);
#pragma unroll
    for (int fm = 0; fm < 4; ++fm)
#pragma unroll
      for (int fn = 0; fn < 4; ++fn)
        acc[fm][fn] = MFMA16(af[fm], bv[fn], acc[fm][fn]);
  }
  __syncthreads();  // all waves done with K-loop POOL reads; overlay begins
                    // (also closes the pre-existing Et2-overlay race)

  // ---- epilogue: streaming exp -> sums + packed fp8 (branchless normal-only) ----
  unsigned int ebw[4][4];
  float rsum[4][4] = {};
  float csum[4] = {};
#pragma unroll
  for (int fm = 0; fm < 4; ++fm)
#pragma unroll
    for (int fn = 0; fn < 4; ++fn) {
      unsigned int pw = 0;
#pragma unroll
      for (int rr = 0; rr < 4; ++rr) {
        float e = __expf(acc[fm][fn][rr]);
        rsum[fm][rr] += e;
        csum[fn] += e;
        pw |= f2fp8n(e) << (8 * rr);
      }
      ebw[fm][fn] = pw;
    }

  float* redp = (float*)(POOL + 18432);   // [4][64] row-sum partials
  float* red2p = (float*)(POOL + 19456);  // [4][64] col-sum partials
#pragma unroll
  for (int fm = 0; fm < 4; ++fm)
#pragma unroll
    for (int rr = 0; rr < 4; ++rr) {
      float s = rsum[fm][rr];
#pragma unroll
      for (int off = 1; off < 16; off <<= 1) s += __shfl_xor(s, off);
      if (lr == 0) redp[w * 64 + fm * 16 + lg * 4 + rr] = s;
    }
  if (!diag) {
#pragma unroll
    for (int fn = 0; fn < 4; ++fn) {
      float cs = csum[fn];
      cs += __shfl_xor(cs, 16);
      cs += __shfl_xor(cs, 32);
      if (lg == 0) red2p[w * 64 + fn * 16 + lr] = cs;
    }
  }

  // transposed-tile bounce ONLY (word writes; rr bytes are contiguous in Et2)
  unsigned char(*Et2)[144] = (unsigned char(*)[144])POOL;  // 18432 B
#pragma unroll
  for (int fm = 0; fm < 4; ++fm)
#pragma unroll
    for (int fn = 0; fn < 4; ++fn)
      *(unsigned int*)&Et2[wc * 64 + fn * 16 + lr][wr * 64 + fm * 16 + lg * 4] =
          ebw[fm][fn];
  __syncthreads();
  {
    unsigned char* dst2 = E8 + ((size_t)(bj * 64 + bi) << 14);
#pragma unroll
    for (int q = 0; q < 4; ++q) {
      const int f = t + q * 256;
      *(uint4*)(dst2 + f * 16) = *(const uint4*)&Et2[f >> 3][(f & 7) * 16];
    }
  }
  if (t < 128) {
    const int wrx = t >> 6, idx = t & 63;
    lpart[(size_t)bj * NN + i0 + t] =
        redp[(2 * wrx) * 64 + idx] + redp[(2 * wrx + 1) * 64 + idx];
  } else if (!diag) {
    const int c = t - 128;
    const int wcx = c >> 6, idx = c & 63;
    lpart[(size_t)bi * NN + j0 + c] =
        red2p[wcx * 64 + idx] + red2p[(2 + wcx) * 64 + idx];
  }
}

// ---------------- K1b: rl = 2^15 / sum(lpart over 64 slots) ----------------
__global__ __launch_bounds__(256) void k_recip(const float* __restrict__ lpart,
                                               float* __restrict__ rl) {
  const int i = blockIdx.x * 256 + threadIdx.x;
  float s = 0.f;
  for (int c = 0; c < 64; ++c) s += lpart[(size_t)c * NN + i];
  rl[i] = CBIG / s;
}

// ---------------- K2: rowsumE wrote the LOWER slot (tj,ti); scale it in place
// (rows are j-range, cols i-range: factor rl[j0+r]+rl[i0+c]) and mirror the
// scaled tile into the UPPER slot (ti,tj) via LDS word-level 4x4 transpose. ----
__global__ __launch_bounds__(256) void k_scale2(unsigned char* __restrict__ P,
                                                const float* __restrict__ rl) {
  __shared__ unsigned int T32[128][35];  // scaled tile, word-granular, padded
  int b = blockIdx.x, ti = 0;
  while (b >= 64 - ti) { b -= 64 - ti; ++ti; }
  const int tj = ti + b;
  const int i0 = ti * 128, j0 = tj * 128;
  const int t = threadIdx.x;
  unsigned char* tileC = P + ((size_t)(tj * 64 + ti) << 14);  // lower slot

  // pass 1: read + scale + write canonical (in place) + stage words into LDS
#pragma unroll
  for (int q = 0; q < 4; ++q) {
    const int f = t + q * 256;      // 1024 chunks of 16B
    const int r = f >> 3;           // row within tile = global row j0+r
    const int c0 = (f & 7) * 16;    // col within tile = global col i0+c
    uint4 v = *(const uint4*)(tileC + f * 16);
    const float rlr = rl[j0 + r];
    float rlc[16];
#pragma unroll
    for (int p = 0; p < 4; ++p) {
      float4 r4 = *(const float4*)(rl + i0 + c0 + p * 4);
      rlc[p * 4 + 0] = r4.x; rlc[p * 4 + 1] = r4.y;
      rlc[p * 4 + 2] = r4.z; rlc[p * 4 + 3] = r4.w;
    }
    unsigned int wsrc[4] = {v.x, v.y, v.z, v.w};
    unsigned int wdst[4];
#pragma unroll
    for (int p = 0; p < 4; ++p) {
      unsigned int in = wsrc[p], out = 0;
#pragma unroll
      for (int k = 0; k < 4; ++k) {
        float e = fp82f((in >> (8 * k)) & 0xffu);
        out |= f2fp8n(e * (rlr + rlc[p * 4 + k])) << (8 * k);
      }
      wdst[p] = out;
      T32[r][(c0 >> 2) + p] = out;
    }
    *(uint4*)(tileC + f * 16) = make_uint4(wdst[0], wdst[1], wdst[2], wdst[3]);
  }
  if (ti == tj) return;  // diagonal: no mirror needed
  __syncthreads();

  // pass 2: upper slot (ti,tj): out[r2][c] = scaled[c][r2]
  unsigned char* tileT = P + ((size_t)(ti * 64 + tj) << 14);
  {
    const int rg = t >> 3;        // out row group (4 rows): r2 = rg*4
    const int cc = t & 7;         // out col chunk: c2 = cc*16
    const int c2 = cc * 16;
    unsigned int o[4][4];  // o[i][k4]: out row rg*4+i, word k4
#pragma unroll
    for (int k4 = 0; k4 < 4; ++k4) {
      unsigned int a0 = T32[c2 + k4 * 4 + 0][rg];
      unsigned int a1 = T32[c2 + k4 * 4 + 1][rg];
      unsigned int a2 = T32[c2 + k4 * 4 + 2][rg];
      unsigned int a3 = T32[c2 + k4 * 4 + 3][rg];
      unsigned int b0 = (a0 & 0x00FF00FFu) | ((a1 << 8) & 0xFF00FF00u);
      unsigned int b1 = ((a0 >> 8) & 0x00FF00FFu) | (a1 & 0xFF00FF00u);
      unsigned int b2 = (a2 & 0x00FF00FFu) | ((a3 << 8) & 0xFF00FF00u);
      unsigned int b3 = ((a2 >> 8) & 0x00FF00FFu) | (a3 & 0xFF00FF00u);
      o[0][k4] = (b0 & 0x0000FFFFu) | (b2 << 16);
      o[1][k4] = (b1 & 0x0000FFFFu) | (b3 << 16);
      o[2][k4] = (b0 >> 16) | (b2 & 0xFFFF0000u);
      o[3][k4] = (b1 >> 16) | (b3 & 0xFFFF0000u);
    }
#pragma unroll
    for (int i = 0; i < 4; ++i)
      *(uint4*)(tileT + (size_t)(rg * 4 + i) * 128 + c2) =
          make_uint4(o[i][0], o[i][1], o[i][2], o[i][3]);
  }
}

// ---------------- K3: parts[z] = bf16((P8t @ x8) * 2^-15), K-split 4 ----------
// Round-2 proven pipeline + round-8 coalesced C-write. NEW (round 12): LDS
// squeezed to EXACTLY 32768 B (bounce done in two 64-row halves, 17408 B each,
// overlaid on the pipeline pool) -> 5 blocks/CU (was 4).
__global__ __launch_bounds__(256, 4) void k_pv3(const unsigned char* __restrict__ P8,
                                                const unsigned char* __restrict__ xT8,
                                                unsigned short* __restrict__ parts) {
  __shared__ __align__(16) unsigned char POOL[32768];
  const int i0 = blockIdx.x * 128;
  const int n0 = blockIdx.y * 128;
  const int z = blockIdx.z;
  const int t = threadIdx.x;
  const int w = t >> 6, l = t & 63;
  const int lr = l & 15, lg = l >> 4;
  const int wr = w >> 1, wc = w & 1;
  const int r0 = w * 16 + (l >> 2);
  const int clog = (l & 3) ^ ((r0 >> 1) & 3);
  const unsigned char* Abase = P8 + ((size_t)((i0 >> 7) * 64 + z * 16) << 14) +
                               r0 * 128 + clog * 16;
  const unsigned char* gB = xT8 + (size_t)(n0 + r0) * NN + z * 2048 + clog * 16;

#define PV_STAGE(s, koff)                                                      \
  do {                                                                         \
    const unsigned char* a_ = Abase + (((koff) >> 7) << 14) + ((koff) & 127);  \
    GLL16(a_, POOL + (s) * 8192 + w * 1024);                                   \
    GLL16(a_ + 8192, POOL + (s) * 8192 + 4096 + w * 1024);                     \
    GLL16(gB + (koff), POOL + 16384 + (s) * 8192 + w * 1024);                  \
    GLL16(gB + (size_t)64 * NN + (koff),                                       \
          POOL + 16384 + (s) * 8192 + 4096 + w * 1024);                        \
  } while (0)

  PV_STAGE(0, 0);
  PV_STAGE(1, 64);

  f32x4 acc[4][4] = {};
  for (int ks = 0; ks < 32; ++ks) {
    if (ks + 1 < 32) { WAITV4(); } else { WAITV0(); }
    BAR(); FENCE();
    const char* AS = (const char*)(POOL + (ks & 1) * 8192);
    const char* BS = (const char*)(POOL + 16384 + (ks & 1) * 8192);
    unsigned long long af[4][2], bv[4][2];
#pragma unroll
    for (int fm = 0; fm < 4; ++fm) {
      const int row = wr * 64 + fm * 16 + lr;
      const int swz = (row >> 1) & 3;
#pragma unroll
      for (int kk = 0; kk < 2; ++kk) {
        int off = row * 64 + (((kk * 2 + (lg >> 1)) ^ swz) << 4) + ((lg & 1) << 3);
        af[fm][kk] = *(const unsigned long long*)(AS + off);
      }
    }
#pragma unroll
    for (int fn = 0; fn < 4; ++fn) {
      const int row = wc * 64 + fn * 16 + lr;
      const int swz = (row >> 1) & 3;
#pragma unroll
      for (int kk = 0; kk < 2; ++kk) {
        int off = row * 64 + (((kk * 2 + (lg >> 1)) ^ swz) << 4) + ((lg & 1) << 3);
        bv[fn][kk] = *(const unsigned long long*)(BS + off);
      }
    }
    WAITLGKM0();
    BAR(); FENCE();
    if (ks + 2 < 32) PV_STAGE(ks & 1, (ks + 2) * 64);
#pragma unroll
    for (int kk = 0; kk < 2; ++kk)
#pragma unroll
      for (int fm = 0; fm < 4; ++fm)
#pragma unroll
        for (int fn = 0; fn < 4; ++fn)
          acc[fm][fn] = MFMA8(af[fm][kk], bv[fn][kk], acc[fm][fn]);
  }

  // ---- epilogue: two-half LDS bounce -> coalesced uint4 stores ----
  __syncthreads();  // all waves done reading pipeline LDS
  unsigned short* Pt = (unsigned short*)POOL;  // [64 rows][136 shorts] per half
#pragma unroll
  for (int half = 0; half < 2; ++half) {
    if (wr == half) {
#pragma unroll
      for (int fm = 0; fm < 4; ++fm)
#pragma unroll
        for (int fn = 0; fn < 4; ++fn) {
          const int col = wc * 64 + fn * 16 + lr;
#pragma unroll
          for (int rr = 0; rr < 4; ++rr) {
            const int rloc = fm * 16 + lg * 4 + rr;
            Pt[rloc * 136 + col] = f2bf(acc[fm][fn][rr] * INV_CBIG);
          }
        }
    }
    __syncthreads();
    {
      unsigned short* dst = parts + (size_t)z * NN * DD +
                            (size_t)(i0 + half * 64) * DD + n0;
#pragma unroll
      for (int q = 0; q < 4; ++q) {
        const int f = t + q * 256;        // 1024 chunks of 16B (64 rows)
        const int row = f >> 4, ch = f & 15;
        *(uint4*)(dst + (size_t)row * DD + ch * 8) =
            *(const uint4*)&Pt[row * 136 + ch * 8];
      }
    }
    if (half == 0) __syncthreads();
  }
}

// ---------------- K4: y = x - SCALE*sum(parts), LayerNorm ----------------
// Round-10 wave-per-row: 2048 blocks x 256 threads, shfl-only reductions.
__global__ __launch_bounds__(256) void k_ln(const float* __restrict__ x,
                                            float* __restrict__ out,
                                            const unsigned short* __restrict__ parts,
                                            const float* __restrict__ gamma,
                                            const float* __restrict__ beta) {
  const int row = blockIdx.x * 4 + (threadIdx.x >> 6);
  const int l = threadIdx.x & 63;
  const int c0 = l * 8;

  float p[8] = {};
#pragma unroll
  for (int s = 0; s < 4; ++s) {
    uint4 q = *(const uint4*)(parts + (size_t)s * NN * DD + (size_t)row * DD + c0);
    unsigned int wq[4] = {q.x, q.y, q.z, q.w};
#pragma unroll
    for (int j = 0; j < 4; ++j) {
      p[2 * j + 0] += __builtin_bit_cast(float, wq[j] << 16);
      p[2 * j + 1] += __builtin_bit_cast(float, wq[j] & 0xFFFF0000u);
    }
  }
  float4 xv0 = *(const float4*)(x + (size_t)row * DD + c0);
  float4 xv1 = *(const float4*)(x + (size_t)row * DD + c0 + 4);
  float y[8];
  y[0] = xv0.x - SCALE_C * p[0];
  y[1] = xv0.y - SCALE_C * p[1];
  y[2] = xv0.z - SCALE_C * p[2];
  y[3] = xv0.w - SCALE_C * p[3];
  y[4] = xv1.x - SCALE_C * p[4];
  y[5] = xv1.y - SCALE_C * p[5];
  y[6] = xv1.z - SCALE_C * p[6];
  y[7] = xv1.w - SCALE_C * p[7];

  float sum = 0.f;
#pragma unroll
  for (int j = 0; j < 8; ++j) sum += y[j];
#pragma unroll
  for (int off = 1; off < 64; off <<= 1) sum += __shfl_xor(sum, off);
  const float mean = sum * (1.0f / DD);

  float d[8], vs = 0.f;
#pragma unroll
  for (int j = 0; j < 8; ++j) {
    d[j] = y[j] - mean;
    vs += d[j] * d[j];
  }
#pragma unroll
  for (int off = 1; off < 64; off <<= 1) vs += __shfl_xor(vs, off);
  const float rstd = rsqrtf(vs * (1.0f / DD) + LN_EPS_C);

  float4 g0 = *(const float4*)(gamma + c0);
  float4 g1 = *(const float4*)(gamma + c0 + 4);
  float4 b0 = *(const float4*)(beta + c0);
  float4 b1 = *(const float4*)(beta + c0 + 4);
  float4 o0, o1;
  o0.x = d[0] * rstd * g0.x + b0.x;
  o0.y = d[1] * rstd * g0.y + b0.y;
  o0.z = d[2] * rstd * g0.z + b0.z;
  o0.w = d[3] * rstd * g0.w + b0.w;
  o1.x = d[4] * rstd * g1.x + b1.x;
  o1.y = d[5] * rstd * g1.y + b1.y;
  o1.z = d[6] * rstd * g1.z + b1.z;
  o1.w = d[7] * rstd * g1.w + b1.w;
  *(float4*)(out + (size_t)row * DD + c0) = o0;
  *(float4*)(out + (size_t)row * DD + c0 + 4) = o1;
}

extern "C" void kernel_launch(void* const* d_in, const int* in_sizes, int n_in,
                              void* d_out, int out_size, void* d_ws, size_t ws_size,
                              hipStream_t stream) {
  const float* x = (const float*)d_in[0];
  const float* gamma = (const float*)d_in[1];
  const float* beta = (const float*)d_in[2];
  float* out = (float*)d_out;

  unsigned short* xnb = (unsigned short*)d_ws;               // 8 MB (bf16 xn)
  unsigned char* xT8 = (unsigned char*)(xnb + (size_t)NN * DD);  // 4 MB (fp8 xT)
  float* lpart = (float*)(xT8 + (size_t)NN * DD);            // 2 MB
  float* rl = lpart + (size_t)64 * NN;                       // 32 KB
  unsigned short* parts = (unsigned short*)(rl + NN);        // 32 MB (4 bf16 slices)
  unsigned char* E8 = (unsigned char*)(parts + (size_t)4 * NN * DD);  // 64 MB tiled
  // total ~110 MB; 162 MB proven available in rounds 4-16

  k_prep2<<<NN / 16, 256, 0, stream>>>(x, xnb, xT8);
  k_rowsumE<<<2080, 256, 0, stream>>>(xnb, lpart, E8);
  k_recip<<<NN / 256, 256, 0, stream>>>(lpart, rl);
  k_scale2<<<2080, 256, 0, stream>>>(E8, rl);
  k_pv3<<<dim3(64, 4, 4), 256, 0, stream>>>(E8, xT8, parts);
  k_ln<<<NN / 4, 256, 0, stream>>>(x, out, parts, gamma, beta);
}

// Round 14
// 147.130 us; speedup vs baseline: 1.1394x; 1.0035x over previous
//
#include <hip/hip_runtime.h>
#include <math.h>

#define NN 8192
#define DD 512

constexpr float SCALE_C = 0.1f;
constexpr float LN_EPS_C = 1e-6f;
constexpr float NORM_EPS_C = 1e-12f;
constexpr float CBIG = 32768.0f;        // P stored as P*2^15 in fp8
constexpr float INV_CBIG = 1.0f / 32768.0f;

typedef __attribute__((ext_vector_type(8))) short bf16x8;
typedef __attribute__((ext_vector_type(4))) float f32x4;

#define MFMA16(a, b, c) __builtin_amdgcn_mfma_f32_16x16x32_bf16((a), (b), (c), 0, 0, 0)
#define MFMA8(a, b, c)                                                        \
  __builtin_amdgcn_mfma_f32_16x16x32_fp8_fp8((long)(a), (long)(b), (c), 0, 0, 0)

#define GLL16(g, l)                                                        \
  __builtin_amdgcn_global_load_lds(                                        \
      (const __attribute__((address_space(1))) unsigned int*)(g),          \
      (__attribute__((address_space(3))) unsigned int*)(l), 16, 0, 0)

#define WAITV4() asm volatile("s_waitcnt vmcnt(4)" ::: "memory")
#define WAITV0() asm volatile("s_waitcnt vmcnt(0)" ::: "memory")
#define WAITLGKM0() asm volatile("s_waitcnt lgkmcnt(0)" ::: "memory")
#define FENCE() asm volatile("" ::: "memory")
#define BAR() __builtin_amdgcn_s_barrier()

__device__ inline unsigned short f2bf(float f) {
  unsigned int u = __builtin_bit_cast(unsigned int, f);
  unsigned int r = (u + 0x7FFFu + ((u >> 16) & 1u)) >> 16;
  return (unsigned short)r;
}

// f32 -> fp8 e4m3fn, RNE, POSITIVE NORMAL ONLY (valid for E=exp(S) in [0.37,2.72])
__device__ inline unsigned int f2fp8n(float f) {
  unsigned int a = __builtin_bit_cast(unsigned int, f);
  unsigned int r = a + 0x7FFFFu + ((a >> 20) & 1u);
  return (r >> 20) - 960u;
}

// f32 -> fp8 e4m3fn (OCP), RNE, subnormal-aware (for x values in k_prep2)
__device__ inline unsigned int f2fp8(float f) {
  unsigned int u = __builtin_bit_cast(unsigned int, f);
  unsigned int s = (u >> 24) & 0x80u;
  unsigned int a = u & 0x7fffffffu;
  if (a >= 0x3C800000u) {  // >= 2^-6: normal
    unsigned int r = a + 0x7FFFFu + ((a >> 20) & 1u);
    return s | ((r >> 20) - 960u);
  }
  float af = __builtin_bit_cast(float, a);
  return s | (unsigned int)(int)rintf(af * 512.0f);  // subnormal: m * 2^-9
}

// fp8 e4m3 (positive, normal) -> f32
__device__ inline float fp82f(unsigned int b) {
  return __builtin_bit_cast(float, (b + 960u) << 20);
}

// ---------------- K0 (fused): xnb = bf16(x/||x||) AND xT8[d][j] = fp8(x[j][d]).
// 512 blocks x 256 threads, 16 rows per block. x read ONCE (was twice).
__global__ __launch_bounds__(256) void k_prep2(const float* __restrict__ x,
                                               unsigned short* __restrict__ xnb,
                                               unsigned char* __restrict__ xT8) {
  __shared__ unsigned int T8w[16][130];  // 16 rows x 512 fp8 bytes (word-packed, +2 pad)
  const int j0 = blockIdx.x * 16;
  const int t = threadIdx.x;
  const int tr = t >> 4, tc = t & 15;   // 16 threads per row
  const int row = j0 + tr;
  const float* xr = x + (size_t)row * DD;
  float4 v[8];
  float ss = 0.f;
#pragma unroll
  for (int k = 0; k < 8; ++k) {
    v[k] = *(const float4*)(xr + tc * 4 + k * 64);
    ss += v[k].x * v[k].x + v[k].y * v[k].y + v[k].z * v[k].z + v[k].w * v[k].w;
  }
#pragma unroll
  for (int off = 1; off < 16; off <<= 1) ss += __shfl_xor(ss, off);
  const float rn = 1.0f / fmaxf(sqrtf(ss), NORM_EPS_C);
#pragma unroll
  for (int k = 0; k < 8; ++k) {
    ushort4 o;
    o.x = f2bf(v[k].x * rn);
    o.y = f2bf(v[k].y * rn);
    o.z = f2bf(v[k].z * rn);
    o.w = f2bf(v[k].w * rn);
    *(ushort4*)(xnb + (size_t)row * DD + tc * 4 + k * 64) = o;
    T8w[tr][tc + k * 16] = f2fp8(v[k].x) | (f2fp8(v[k].y) << 8) |
                           (f2fp8(v[k].z) << 16) | (f2fp8(v[k].w) << 24);
  }
  __syncthreads();
  // transpose out: each thread handles 2 d-values, gathers 16 bytes (column d)
#pragma unroll
  for (int q = 0; q < 2; ++q) {
    const int d = t + q * 256;
    const unsigned char* col = (const unsigned char*)&T8w[0][0] + d;  // stride 520
    unsigned int wds[4];
#pragma unroll
    for (int p = 0; p < 4; ++p)
      wds[p] = (unsigned int)col[(p * 4 + 0) * 520] |
               ((unsigned int)col[(p * 4 + 1) * 520] << 8) |
               ((unsigned int)col[(p * 4 + 2) * 520] << 16) |
               ((unsigned int)col[(p * 4 + 3) * 520] << 24);
    *(uint4*)&xT8[(size_t)d * NN + j0] = make_uint4(wds[0], wds[1], wds[2], wds[3]);
  }
}

// ---------------- K1: symmetric S-GEMM (bf16) -> tiled fp8 E + l partials ------
// E8 layout: tile (a,b) contiguous 16 KB at (a*64+b)*16384, row-major inside.
// Round-2 proven 2-slot / 2-barrier / vmcnt(4) pipeline. Round-7: transposed-
// slot-only word-granular bounce. Round-12: LDS at EXACTLY 32768 B (red/red2
// overlaid into POOL post-K-loop) -> 5 blocks/CU. Measured 57.4 µs.
__global__ __launch_bounds__(256, 4) void k_rowsumE(const unsigned short* __restrict__ xnb,
                                                    float* __restrict__ lpart,
                                                    unsigned char* __restrict__ E8) {
  __shared__ __align__(16) unsigned char POOL[32768];
  // K-loop: 2 x 16 KB stage slots. Epilogue overlay: Et2[128][144] at +0
  // (18432 B), red[4][64] f32 at +18432, red2[4][64] f32 at +19456.

  int b = blockIdx.x, bi = 0;
  while (b >= 64 - bi) { b -= 64 - bi; ++bi; }
  const int bj = bi + b;
  const int i0 = bi * 128, j0 = bj * 128;
  const int diag = (bi == bj);

  const int t = threadIdx.x;
  const int w = t >> 6, l = t & 63;
  const int lr = l & 15, lg = l >> 4;
  const int wr = w >> 1, wc = w & 1;
  const int r0 = w * 16 + (l >> 2);
  const int clog = (l & 3) ^ ((r0 >> 1) & 3);
  const unsigned short* gA = xnb + (size_t)(i0 + r0) * DD + clog * 8;
  const unsigned short* gB = xnb + (size_t)(j0 + r0) * DD + clog * 8;

#define RS_STAGE(s, koff)                                                        \
  do {                                                                           \
    GLL16(gA + (koff), (unsigned short*)(POOL + (s) * 16384) + w * 512);         \
    GLL16(gA + (size_t)64 * DD + (koff),                                         \
          (unsigned short*)(POOL + (s) * 16384 + 4096) + w * 512);               \
    GLL16(gB + (koff), (unsigned short*)(POOL + (s) * 16384 + 8192) + w * 512);  \
    GLL16(gB + (size_t)64 * DD + (koff),                                         \
          (unsigned short*)(POOL + (s) * 16384 + 12288) + w * 512);              \
  } while (0)

  RS_STAGE(0, 0);
  RS_STAGE(1, 32);

  f32x4 acc[4][4] = {};
  for (int ks = 0; ks < 16; ++ks) {
    if (ks + 1 < 16) { WAITV4(); } else { WAITV0(); }
    BAR(); FENCE();
    const char* AS = (const char*)(POOL + (ks & 1) * 16384);
    const char* BS = AS + 8192;
    bf16x8 af[4], bv[4];
#pragma unroll
    for (int fm = 0; fm < 4; ++fm) {
      const int row = wr * 64 + fm * 16 + lr;
      af[fm] = *(const bf16x8*)(AS + row * 64 + ((lg ^ ((row >> 1) & 3)) << 4));
    }
#pragma unroll
    for (int fn = 0; fn < 4; ++fn) {
      const int row = wc * 64 + fn * 16 + lr;
      bv[fn] = *(const bf16x8*)(BS + row * 64 + ((lg ^ ((row >> 1) & 3)) << 4));
    }
    WAITLGKM0();
    BAR(); FENCE();
    if (ks + 2 < 16) RS_STAGE(ks & 1, (size_t)(ks + 2) * 32);
#pragma unroll
    for (int fm = 0; fm < 4; ++fm)
#pragma unroll
      for (int fn = 0; fn < 4; ++fn)
        acc[fm][fn] = MFMA16(af[fm], bv[fn], acc[fm][fn]);
  }
  __syncthreads();  // all waves done with K-loop POOL reads; overlay begins

  // ---- epilogue: streaming exp -> sums + packed fp8 (branchless normal-only) ----
  unsigned int ebw[4][4];
  float rsum[4][4] = {};
  float csum[4] = {};
#pragma unroll
  for (int fm = 0; fm < 4; ++fm)
#pragma unroll
    for (int fn = 0; fn < 4; ++fn) {
      unsigned int pw = 0;
#pragma unroll
      for (int rr = 0; rr < 4; ++rr) {
        float e = __expf(acc[fm][fn][rr]);
        rsum[fm][rr] += e;
        csum[fn] += e;
        pw |= f2fp8n(e) << (8 * rr);
      }
      ebw[fm][fn] = pw;
    }

  float* redp = (float*)(POOL + 18432);   // [4][64] row-sum partials
  float* red2p = (float*)(POOL + 19456);  // [4][64] col-sum partials
#pragma unroll
  for (int fm = 0; fm < 4; ++fm)
#pragma unroll
    for (int rr = 0; rr < 4; ++rr) {
      float s = rsum[fm][rr];
#pragma unroll
      for (int off = 1; off < 16; off <<= 1) s += __shfl_xor(s, off);
      if (lr == 0) redp[w * 64 + fm * 16 + lg * 4 + rr] = s;
    }
  if (!diag) {
#pragma unroll
    for (int fn = 0; fn < 4; ++fn) {
      float cs = csum[fn];
      cs += __shfl_xor(cs, 16);
      cs += __shfl_xor(cs, 32);
      if (lg == 0) red2p[w * 64 + fn * 16 + lr] = cs;
    }
  }

  // transposed-tile bounce ONLY (word writes; rr bytes are contiguous in Et2)
  unsigned char(*Et2)[144] = (unsigned char(*)[144])POOL;  // 18432 B
#pragma unroll
  for (int fm = 0; fm < 4; ++fm)
#pragma unroll
    for (int fn = 0; fn < 4; ++fn)
      *(unsigned int*)&Et2[wc * 64 + fn * 16 + lr][wr * 64 + fm * 16 + lg * 4] =
          ebw[fm][fn];
  __syncthreads();
  {
    unsigned char* dst2 = E8 + ((size_t)(bj * 64 + bi) << 14);
#pragma unroll
    for (int q = 0; q < 4; ++q) {
      const int f = t + q * 256;
      *(uint4*)(dst2 + f * 16) = *(const uint4*)&Et2[f >> 3][(f & 7) * 16];
    }
  }
  if (t < 128) {
    const int wrx = t >> 6, idx = t & 63;
    lpart[(size_t)bj * NN + i0 + t] =
        redp[(2 * wrx) * 64 + idx] + redp[(2 * wrx + 1) * 64 + idx];
  } else if (!diag) {
    const int c = t - 128;
    const int wcx = c >> 6, idx = c & 63;
    lpart[(size_t)bi * NN + j0 + c] =
        red2p[wcx * 64 + idx] + red2p[(2 + wcx) * 64 + idx];
  }
}

// ---------------- K1b: rl = 2^15 / sum(lpart over 64 slots) ----------------
__global__ __launch_bounds__(256) void k_recip(const float* __restrict__ lpart,
                                               float* __restrict__ rl) {
  const int i = blockIdx.x * 256 + threadIdx.x;
  float s = 0.f;
  for (int c = 0; c < 64; ++c) s += lpart[(size_t)c * NN + i];
  rl[i] = CBIG / s;
}

// ---------------- K2: rowsumE wrote the LOWER slot (tj,ti); scale it in place
// (rows are j-range, cols i-range: factor rl[j0+r]+rl[i0+c]) and mirror the
// scaled tile into the UPPER slot (ti,tj) via LDS word-level 4x4 transpose. ----
__global__ __launch_bounds__(256) void k_scale2(unsigned char* __restrict__ P,
                                                const float* __restrict__ rl) {
  __shared__ unsigned int T32[128][35];  // scaled tile, word-granular, padded
  int b = blockIdx.x, ti = 0;
  while (b >= 64 - ti) { b -= 64 - ti; ++ti; }
  const int tj = ti + b;
  const int i0 = ti * 128, j0 = tj * 128;
  const int t = threadIdx.x;
  unsigned char* tileC = P + ((size_t)(tj * 64 + ti) << 14);  // lower slot

  // pass 1: read + scale + write canonical (in place) + stage words into LDS
#pragma unroll
  for (int q = 0; q < 4; ++q) {
    const int f = t + q * 256;      // 1024 chunks of 16B
    const int r = f >> 3;           // row within tile = global row j0+r
    const int c0 = (f & 7) * 16;    // col within tile = global col i0+c
    uint4 v = *(const uint4*)(tileC + f * 16);
    const float rlr = rl[j0 + r];
    float rlc[16];
#pragma unroll
    for (int p = 0; p < 4; ++p) {
      float4 r4 = *(const float4*)(rl + i0 + c0 + p * 4);
      rlc[p * 4 + 0] = r4.x; rlc[p * 4 + 1] = r4.y;
      rlc[p * 4 + 2] = r4.z; rlc[p * 4 + 3] = r4.w;
    }
    unsigned int wsrc[4] = {v.x, v.y, v.z, v.w};
    unsigned int wdst[4];
#pragma unroll
    for (int p = 0; p < 4; ++p) {
      unsigned int in = wsrc[p], out = 0;
#pragma unroll
      for (int k = 0; k < 4; ++k) {
        float e = fp82f((in >> (8 * k)) & 0xffu);
        out |= f2fp8n(e * (rlr + rlc[p * 4 + k])) << (8 * k);
      }
      wdst[p] = out;
      T32[r][(c0 >> 2) + p] = out;
    }
    *(uint4*)(tileC + f * 16) = make_uint4(wdst[0], wdst[1], wdst[2], wdst[3]);
  }
  if (ti == tj) return;  // diagonal: no mirror needed
  __syncthreads();

  // pass 2: upper slot (ti,tj): out[r2][c] = scaled[c][r2]
  unsigned char* tileT = P + ((size_t)(ti * 64 + tj) << 14);
  {
    const int rg = t >> 3;        // out row group (4 rows): r2 = rg*4
    const int cc = t & 7;         // out col chunk: c2 = cc*16
    const int c2 = cc * 16;
    unsigned int o[4][4];  // o[i][k4]: out row rg*4+i, word k4
#pragma unroll
    for (int k4 = 0; k4 < 4; ++k4) {
      unsigned int a0 = T32[c2 + k4 * 4 + 0][rg];
      unsigned int a1 = T32[c2 + k4 * 4 + 1][rg];
      unsigned int a2 = T32[c2 + k4 * 4 + 2][rg];
      unsigned int a3 = T32[c2 + k4 * 4 + 3][rg];
      unsigned int b0 = (a0 & 0x00FF00FFu) | ((a1 << 8) & 0xFF00FF00u);
      unsigned int b1 = ((a0 >> 8) & 0x00FF00FFu) | (a1 & 0xFF00FF00u);
      unsigned int b2 = (a2 & 0x00FF00FFu) | ((a3 << 8) & 0xFF00FF00u);
      unsigned int b3 = ((a2 >> 8) & 0x00FF00FFu) | (a3 & 0xFF00FF00u);
      o[0][k4] = (b0 & 0x0000FFFFu) | (b2 << 16);
      o[1][k4] = (b1 & 0x0000FFFFu) | (b3 << 16);
      o[2][k4] = (b0 >> 16) | (b2 & 0xFFFF0000u);
      o[3][k4] = (b1 >> 16) | (b3 & 0xFFFF0000u);
    }
#pragma unroll
    for (int i = 0; i < 4; ++i)
      *(uint4*)(tileT + (size_t)(rg * 4 + i) * 128 + c2) =
          make_uint4(o[i][0], o[i][1], o[i][2], o[i][3]);
  }
}

// ---------------- K3: parts[z] = bf16((P8t @ x8) * 2^-15), K-split 4 ----------
// Round-8 proven form EXACTLY (34816 B pool, single-pass full-tile bounce) —
// r12's 32KB two-half variant measured ~1.3 µs slower in aggregate; reverted.
__global__ __launch_bounds__(256, 4) void k_pv3(const unsigned char* __restrict__ P8,
                                                const unsigned char* __restrict__ xT8,
                                                unsigned short* __restrict__ parts) {
  __shared__ __align__(16) unsigned char POOL[34816];
  const int i0 = blockIdx.x * 128;
  const int n0 = blockIdx.y * 128;
  const int z = blockIdx.z;
  const int t = threadIdx.x;
  const int w = t >> 6, l = t & 63;
  const int lr = l & 15, lg = l >> 4;
  const int wr = w >> 1, wc = w & 1;
  const int r0 = w * 16 + (l >> 2);
  const int clog = (l & 3) ^ ((r0 >> 1) & 3);
  const unsigned char* Abase = P8 + ((size_t)((i0 >> 7) * 64 + z * 16) << 14) +
                               r0 * 128 + clog * 16;
  const unsigned char* gB = xT8 + (size_t)(n0 + r0) * NN + z * 2048 + clog * 16;

#define PV_STAGE(s, koff)                                                      \
  do {                                                                         \
    const unsigned char* a_ = Abase + (((koff) >> 7) << 14) + ((koff) & 127);  \
    GLL16(a_, POOL + (s) * 8192 + w * 1024);                                   \
    GLL16(a_ + 8192, POOL + (s) * 8192 + 4096 + w * 1024);                     \
    GLL16(gB + (koff), POOL + 16384 + (s) * 8192 + w * 1024);                  \
    GLL16(gB + (size_t)64 * NN + (koff),                                       \
          POOL + 16384 + (s) * 8192 + 4096 + w * 1024);                        \
  } while (0)

  PV_STAGE(0, 0);
  PV_STAGE(1, 64);

  f32x4 acc[4][4] = {};
  for (int ks = 0; ks < 32; ++ks) {
    if (ks + 1 < 32) { WAITV4(); } else { WAITV0(); }
    BAR(); FENCE();
    const char* AS = (const char*)(POOL + (ks & 1) * 8192);
    const char* BS = (const char*)(POOL + 16384 + (ks & 1) * 8192);
    unsigned long long af[4][2], bv[4][2];
#pragma unroll
    for (int fm = 0; fm < 4; ++fm) {
      const int row = wr * 64 + fm * 16 + lr;
      const int swz = (row >> 1) & 3;
#pragma unroll
      for (int kk = 0; kk < 2; ++kk) {
        int off = row * 64 + (((kk * 2 + (lg >> 1)) ^ swz) << 4) + ((lg & 1) << 3);
        af[fm][kk] = *(const unsigned long long*)(AS + off);
      }
    }
#pragma unroll
    for (int fn = 0; fn < 4; ++fn) {
      const int row = wc * 64 + fn * 16 + lr;
      const int swz = (row >> 1) & 3;
#pragma unroll
      for (int kk = 0; kk < 2; ++kk) {
        int off = row * 64 + (((kk * 2 + (lg >> 1)) ^ swz) << 4) + ((lg & 1) << 3);
        bv[fn][kk] = *(const unsigned long long*)(BS + off);
      }
    }
    WAITLGKM0();
    BAR(); FENCE();
    if (ks + 2 < 32) PV_STAGE(ks & 1, (ks + 2) * 64);
#pragma unroll
    for (int kk = 0; kk < 2; ++kk)
#pragma unroll
      for (int fm = 0; fm < 4; ++fm)
#pragma unroll
        for (int fn = 0; fn < 4; ++fn)
          acc[fm][fn] = MFMA8(af[fm][kk], bv[fn][kk], acc[fm][fn]);
  }

  // ---- epilogue: LDS bounce -> coalesced uint4 stores ----
  BAR(); FENCE();  // all waves done reading pipeline LDS
  unsigned short* Pt = (unsigned short*)POOL;  // [128 rows][136 shorts] (272B)
#pragma unroll
  for (int fm = 0; fm < 4; ++fm)
#pragma unroll
    for (int fn = 0; fn < 4; ++fn) {
      const int col = wc * 64 + fn * 16 + lr;
#pragma unroll
      for (int rr = 0; rr < 4; ++rr) {
        const int row = wr * 64 + fm * 16 + lg * 4 + rr;
        Pt[row * 136 + col] = f2bf(acc[fm][fn][rr] * INV_CBIG);
      }
    }
  __syncthreads();
  {
    unsigned short* dst = parts + (size_t)z * NN * DD + (size_t)i0 * DD + n0;
#pragma unroll
    for (int q = 0; q < 8; ++q) {
      const int f = t + q * 256;        // 2048 chunks of 16B
      const int row = f >> 4, ch = f & 15;
      *(uint4*)(dst + (size_t)row * DD + ch * 8) =
          *(const uint4*)&Pt[row * 136 + ch * 8];
    }
  }
}

// ---------------- K4: y = x - SCALE*sum(parts), LayerNorm ----------------
// Round-10 wave-per-row: 2048 blocks x 256 threads, shfl-only reductions.
__global__ __launch_bounds__(256) void k_ln(const float* __restrict__ x,
                                            float* __restrict__ out,
                                            const unsigned short* __restrict__ parts,
                                            const float* __restrict__ gamma,
                                            const float* __restrict__ beta) {
  const int row = blockIdx.x * 4 + (threadIdx.x >> 6);
  const int l = threadIdx.x & 63;
  const int c0 = l * 8;

  float p[8] = {};
#pragma unroll
  for (int s = 0; s < 4; ++s) {
    uint4 q = *(const uint4*)(parts + (size_t)s * NN * DD + (size_t)row * DD + c0);
    unsigned int wq[4] = {q.x, q.y, q.z, q.w};
#pragma unroll
    for (int j = 0; j < 4; ++j) {
      p[2 * j + 0] += __builtin_bit_cast(float, wq[j] << 16);
      p[2 * j + 1] += __builtin_bit_cast(float, wq[j] & 0xFFFF0000u);
    }
  }
  float4 xv0 = *(const float4*)(x + (size_t)row * DD + c0);
  float4 xv1 = *(const float4*)(x + (size_t)row * DD + c0 + 4);
  float y[8];
  y[0] = xv0.x - SCALE_C * p[0];
  y[1] = xv0.y - SCALE_C * p[1];
  y[2] = xv0.z - SCALE_C * p[2];
  y[3] = xv0.w - SCALE_C * p[3];
  y[4] = xv1.x - SCALE_C * p[4];
  y[5] = xv1.y - SCALE_C * p[5];
  y[6] = xv1.z - SCALE_C * p[6];
  y[7] = xv1.w - SCALE_C * p[7];

  float sum = 0.f;
#pragma unroll
  for (int j = 0; j < 8; ++j) sum += y[j];
#pragma unroll
  for (int off = 1; off < 64; off <<= 1) sum += __shfl_xor(sum, off);
  const float mean = sum * (1.0f / DD);

  float d[8], vs = 0.f;
#pragma unroll
  for (int j = 0; j < 8; ++j) {
    d[j] = y[j] - mean;
    vs += d[j] * d[j];
  }
#pragma unroll
  for (int off = 1; off < 64; off <<= 1) vs += __shfl_xor(vs, off);
  const float rstd = rsqrtf(vs * (1.0f / DD) + LN_EPS_C);

  float4 g0 = *(const float4*)(gamma + c0);
  float4 g1 = *(const float4*)(gamma + c0 + 4);
  float4 b0 = *(const float4*)(beta + c0);
  float4 b1 = *(const float4*)(beta + c0 + 4);
  float4 o0, o1;
  o0.x = d[0] * rstd * g0.x + b0.x;
  o0.y = d[1] * rstd * g0.y + b0.y;
  o0.z = d[2] * rstd * g0.z + b0.z;
  o0.w = d[3] * rstd * g0.w + b0.w;
  o1.x = d[4] * rstd * g1.x + b1.x;
  o1.y = d[5] * rstd * g1.y + b1.y;
  o1.z = d[6] * rstd * g1.z + b1.z;
  o1.w = d[7] * rstd * g1.w + b1.w;
  *(float4*)(out + (size_t)row * DD + c0) = o0;
  *(float4*)(out + (size_t)row * DD + c0 + 4) = o1;
}

extern "C" void kernel_launch(void* const* d_in, const int* in_sizes, int n_in,
                              void* d_out, int out_size, void* d_ws, size_t ws_size,
                              hipStream_t stream) {
  const float* x = (const float*)d_in[0];
  const float* gamma = (const float*)d_in[1];
  const float* beta = (const float*)d_in[2];
  float* out = (float*)d_out;

  unsigned short* xnb = (unsigned short*)d_ws;               // 8 MB (bf16 xn)
  unsigned char* xT8 = (unsigned char*)(xnb + (size_t)NN * DD);  // 4 MB (fp8 xT)
  float* lpart = (float*)(xT8 + (size_t)NN * DD);            // 2 MB
  float* rl = lpart + (size_t)64 * NN;                       // 32 KB
  unsigned short* parts = (unsigned short*)(rl + NN);        // 32 MB (4 bf16 slices)
  unsigned char* E8 = (unsigned char*)(parts + (size_t)4 * NN * DD);  // 64 MB tiled
  // total ~110 MB; 162 MB proven available in rounds 4-16

  k_prep2<<<NN / 16, 256, 0, stream>>>(x, xnb, xT8);
  k_rowsumE<<<2080, 256, 0, stream>>>(xnb, lpart, E8);
  k_recip<<<NN / 256, 256, 0, stream>>>(lpart, rl);
  k_scale2<<<2080, 256, 0, stream>>>(E8, rl);
  k_pv3<<<dim3(64, 4, 4), 256, 0, stream>>>(E8, xT8, parts);
  k_ln<<<NN / 4, 256, 0, stream>>>(x, out, parts, gamma, beta);
}